// Round 13
// baseline (301.155 us; speedup 1.0000x reference)
//
#include <hip/hip_runtime.h>
#include <hip/hip_fp16.h>
#include <math.h>

constexpr int cB   = 4;
constexpr int cNL  = 150;
constexpr int cNP  = 550;
constexpr int cN   = 700;
constexpr int cH   = 128;
constexpr int cHeads = 4;
constexpr int cL   = 6;
constexpr int cK   = 48;
constexpr int cPF  = 27;
constexpr int cNC  = 13;
constexpr int cFLAT = cN * cH;       // 89600
constexpr int cEdges = cB * cN * cK; // 134400

constexpr int   TABN = 4096;
#define TAB_DMAX 11.0f
#define TAB_HT   (TAB_DMAX / (float)(TABN - 1))
#define TAB_INV  ((float)(TABN - 1) / TAB_DMAX)

#define RBF_STEP (10.0f / 127.0f)
#define RBF_COEFF (-0.5f / (RBF_STEP * RBF_STEP))
#define LOG2F_C 0.69314718055994530942f

__device__ __forceinline__ float sspf(float x) {
    float ax = fabsf(x);
    return fmaxf(x, 0.0f) + __logf(1.0f + __expf(-ax)) - LOG2F_C;
}

__device__ __forceinline__ int mbcnt64(unsigned long long m) {
    return __builtin_amdgcn_mbcnt_hi((unsigned)(m >> 32),
           __builtin_amdgcn_mbcnt_lo((unsigned)m, 0));
}

// ---------------- fused: weight transposes + embedding ----------------
__global__ void __launch_bounds__(256) k_init(
    const float* __restrict__ wq, const float* __restrict__ wk, const float* __restrict__ wv,
    const float* __restrict__ wkn1_w, const float* __restrict__ wvn1_w,
    const float* __restrict__ wkn2_w, const float* __restrict__ wvn2_w,
    const float* __restrict__ wvl_w,
    const float* __restrict__ cen_w, const float* __restrict__ out_w,
    float* __restrict__ wqT, float* __restrict__ wkT, float* __restrict__ wvT,
    float* __restrict__ w1Tk, float* __restrict__ w1Tv,
    float* __restrict__ w2Tk, float* __restrict__ w2Tv,
    float* __restrict__ wvlT,
    float* __restrict__ cenT, float* __restrict__ outT,
    const float* __restrict__ state, const float* __restrict__ ppv,
    const float* __restrict__ w_prot, const float* __restrict__ b_prot,
    const float* __restrict__ w_lig, const float* __restrict__ b_lig,
    float* __restrict__ h, float* __restrict__ pos)
{
    if (blockIdx.x < 1320) {
        int idx = blockIdx.x * 256 + threadIdx.x;
        if (idx < 3 * 24576) {
            int seg = idx / 24576, i = idx % 24576;
            const float* src = seg == 0 ? wq : (seg == 1 ? wk : wv);
            float* dst = seg == 0 ? wqT : (seg == 1 ? wkT : wvT);
            int l = i / 4096, r = i % 4096;
            int hh = r / 1024, r2 = r % 1024;
            int d = r2 / 32, k = r2 % 32;
            dst[i] = src[(((size_t)l * 4 + hh) * 32 + k) * 32 + d];
            return;
        }
        idx -= 3 * 24576;
        if (idx < 2 * 24576) {
            int seg = idx / 24576, i = idx % 24576;
            const float* src = seg == 0 ? wkn1_w : wvn1_w;
            float* dst = seg == 0 ? w1Tk : w1Tv;
            int l = i / 4096, r = i % 4096;
            int c = r / 32, o = r % 32;
            dst[i] = src[((size_t)l * 32 + o) * 128 + c];
            return;
        }
        idx -= 2 * 24576;
        if (idx < 3 * 6144) {
            int seg = idx / 6144, i = idx % 6144;
            const float* src = seg == 0 ? wkn2_w : (seg == 1 ? wvn2_w : wvl_w);
            float* dst = seg == 0 ? w2Tk : (seg == 1 ? w2Tv : wvlT);
            int l = i / 1024, r = i % 1024;
            int c = r / 32, o = r % 32;
            dst[i] = src[((size_t)l * 32 + o) * 32 + c];
            return;
        }
        idx -= 3 * 6144;
        int seg = idx / 98304, i = idx % 98304;
        const float* src = seg == 0 ? cen_w : out_w;
        float* dst = seg == 0 ? cenT : outT;
        int l = i / 16384, r = i % 16384;
        int ii = r / 128, o = r % 128;
        dst[i] = src[((size_t)l * 128 + o) * 128 + ii];
        return;
    }
    // ---- embed: 2 nodes per block ----
    int rel = blockIdx.x - 1320;
    int node = rel * 2 + (threadIdx.x >> 7);
    int b = node / cN, n = node % cN;
    int o = threadIdx.x & 127;
    int lane = threadIdx.x & 63;
    float out;
    if (n < cNP) {
        const float* src = ppv + ((size_t)b * cNP + n) * 30;
        float v = (lane < 30) ? src[lane] : 0.f;
        float s = b_prot[o];
        #pragma unroll
        for (int f = 0; f < cPF; f++) s += w_prot[o * cPF + f] * __shfl(v, 3 + f);
        out = s;
        if (o < 3) pos[((size_t)b * cN + n) * 3 + o] = v;
    } else {
        int nl = n - cNP;
        const float* src = state + ((size_t)b * cNL + nl) * 4;
        float v = (lane < 4) ? src[lane] : 0.f;
        int t = (int)__shfl(v, 3);
        out = w_lig[o * cNC + t] + b_lig[o];
        if (o < 3) pos[((size_t)b * cN + n) * 3 + o] = v;
    }
    h[((size_t)b * cN + n) * cH + o] = out;
}

// ---------------- KNN (radix-select) + edge-MLP table build (float4 kv-pair) + qkv(l=0) ----------------
__global__ void __launch_bounds__(256) k_knn(
    const float* __restrict__ pos, int* __restrict__ nbr, float* __restrict__ dist,
    const float* __restrict__ w1Tk, const float* __restrict__ wkn1_b,
    const float* __restrict__ w2Tk, const float* __restrict__ wkn2_b,
    const float* __restrict__ w1Tv, const float* __restrict__ wvn1_b,
    const float* __restrict__ w2Tv, const float* __restrict__ wvn2_b,
    float* __restrict__ tabP,
    const float* __restrict__ hbuf,
    const float* __restrict__ wqT, const float* __restrict__ wkT, const float* __restrict__ wvT,
    float* __restrict__ q0, __half2* __restrict__ kv0)
{
    int tid = threadIdx.x;
    if (blockIdx.x < cN) {
        // ---- knn: one wave per node, radix-select on float bit patterns ----
        int lane = tid & 63;
        int node = blockIdx.x * 4 + (tid >> 6);
        int b = node / cN, n = node % cN;
        const float* pb = pos + (size_t)b * cN * 3;
        float px = pb[n * 3 + 0], py = pb[n * 3 + 1], pz = pb[n * 3 + 2];
        float d2v[11];
        #pragma unroll
        for (int s = 0; s < 11; s++) {
            int j = lane + s * 64;
            float d2 = 1e30f;
            if (j < cN) {
                float dx = pb[j * 3 + 0] - px;
                float dy = pb[j * 3 + 1] - py;
                float dz = pb[j * 3 + 2] - pz;
                d2 = dx * dx + dy * dy + dz * dz;
                if (j == n) d2 = 1e9f;
            }
            d2v[s] = d2;
        }
        unsigned p = 0;
        for (int bit = 30; bit >= 0; --bit) {
            unsigned t = p | (1u << bit);
            int cnt = 0;
            #pragma unroll
            for (int s = 0; s < 11; s++)
                cnt += __popcll(__ballot(__float_as_uint(d2v[s]) < t));
            if (cnt <= 47) p = t;
        }
        int c_lt = 0;
        #pragma unroll
        for (int s = 0; s < 11; s++)
            c_lt += __popcll(__ballot(__float_as_uint(d2v[s]) < p));
        int base = 0, ebase = c_lt, need = 48 - c_lt;
        #pragma unroll
        for (int s = 0; s < 11; s++) {
            unsigned u = __float_as_uint(d2v[s]);
            unsigned long long blt = __ballot(u < p);
            unsigned long long beq = __ballot(u == p);
            int posn = -1;
            int bl = mbcnt64(blt);
            if (u < p) posn = base + bl;
            base += __popcll(blt);
            int r = mbcnt64(beq);
            int cs = __popcll(beq);
            int take = need < cs ? need : cs;
            if (u == p && r < take) posn = ebase + r;
            ebase += take; need -= take;
            if (posn >= 0) {
                nbr[(size_t)node * cK + posn] = s * 64 + lane;
                dist[(size_t)node * cK + posn] = sqrtf(d2v[s]);
            }
        }
        return;
    }
    if (blockIdx.x < cN + TABN / 4) {
        // ---- table build: wave per entry; float4 kv-pair layout:
        // float4 slot [(l*TABN+e)*32 + c] = { k[e], k[e+1], v[e], v[e+1] }
        // side 0 writes .x at e and .y at e-1; side 1 writes .z at e and .w at e-1.
        int rel = blockIdx.x - cN;
        int lane = tid & 63;
        int e = rel * 4 + (tid >> 6);
        int side = lane >> 5, o = lane & 31;
        float d = (float)e * TAB_HT;
        float z = d * (127.0f / 10.0f);
        int c0 = (int)floorf(z) - 7;
        c0 = c0 < 0 ? 0 : (c0 > 112 ? 112 : c0);
        int i = lane & 15;
        float tt = d - RBF_STEP * (float)(c0 + i);
        float eav = __expf(RBF_COEFF * tt * tt);
        const float* w1T = (side ? w1Tv : w1Tk);
        const float* b1  = (side ? wvn1_b : wkn1_b);
        const float* w2T = (side ? w2Tv : w2Tk);
        const float* b2  = (side ? wvn2_b : wkn2_b);
        int srcb = side * 32;
        for (int l = 0; l < cL; l++) {
            float s = b1[l * 32 + o];
            const float* w1p = w1T + (size_t)l * 4096;
            #pragma unroll
            for (int ii = 0; ii < 16; ii++)
                s += w1p[(c0 + ii) * 32 + o] * __shfl(eav, ii);
            float t1 = sspf(s);
            float s2 = b2[l * 32 + o];
            const float* w2p = w2T + (size_t)l * 1024;
            #pragma unroll
            for (int cc = 0; cc < 32; cc++)
                s2 += w2p[cc * 32 + o] * __shfl(t1, srcb + cc);
            tabP[(((size_t)l * TABN + e) * 32 + o) * 4 + side * 2] = s2;
            if (e > 0)
                tabP[(((size_t)l * TABN + (e - 1)) * 32 + o) * 4 + side * 2 + 1] = s2;
        }
        return;
    }
    // ---- qkv for layer 0: 2 nodes per block; K/V stored interleaved (half2) ----
    int bn = (blockIdx.x - cN - TABN / 4) * 2 + (tid >> 7);
    int o = tid & 127;
    int hh = o >> 5, kq = o & 31;
    float hval = hbuf[(size_t)bn * cH + o];
    size_t wo = ((size_t)0 * 4 + hh) * 1024;
    const float* bq = wqT + wo;
    const float* bk = wkT + wo;
    const float* bv = wvT + wo;
    int srcb = (hh & 1) * 32;
    float sq = 0.f, sk = 0.f, sv = 0.f;
    #pragma unroll
    for (int d = 0; d < 32; d++) {
        float x = __shfl(hval, srcb + d);
        sq += bq[d * 32 + kq] * x;
        sk += bk[d * 32 + kq] * x;
        sv += bv[d * 32 + kq] * x;
    }
    q0[(size_t)bn * cH + o] = sq;
    kv0[(size_t)bn * cH + o] = __halves2half2(__float2half(sk), __float2half(sv));
}

// ---------------- fused attention + LN + residual MLP + next-layer qkv ----------------
// R12 structure (online softmax, 128T/node, 3 barriers) + float4 kv-pair tab:
// per edge-pair each lane issues 2 half2 KV gathers + ONE float4 tab load that
// carries both lerp pairs (w_k and w_v). 25% fewer loads in the single drain
// loop at identical register payload; unroll widened 4->6.
__global__ void __launch_bounds__(128) k_attn(
    int l,
    const float* __restrict__ h_in, const float* __restrict__ qr,
    const __half2* __restrict__ kvr,
    const int* __restrict__ nbr, const float* __restrict__ dist,
    const float* __restrict__ tabP,
    const float* __restrict__ wkl_w,
    const float* __restrict__ wvlT, const float* __restrict__ wvl_b,
    const float* __restrict__ cenT, const float* __restrict__ cen_b,
    const float* __restrict__ outT, const float* __restrict__ out_b,
    const float* __restrict__ ln_g, const float* __restrict__ ln_b,
    float* __restrict__ h_out,
    float* __restrict__ qw, __half2* __restrict__ kvw,
    const float* __restrict__ wqT, const float* __restrict__ wkT, const float* __restrict__ wvT)
{
    int o = threadIdx.x;              // 0..127
    int lane = o & 63;
    int bn = blockIdx.x;
    int b = bn / cN;
    int hh = o >> 5, c = o & 31;
    int srcb = (hh & 1) * 32;
    int hi = lane >> 5;               // 0: lower half-wave, 1: upper

    __shared__ float sh_h[cH];
    __shared__ float sh_t[cH];
    __shared__ int   sh_nb[cK];
    __shared__ int   sh_idx[cK];
    __shared__ float sh_frac[cK];
    __shared__ float red[2][2];

    sh_h[o] = h_in[(size_t)bn * cH + o];
    float qv = qr[(size_t)bn * cH + o];
    if (o < cK) {
        sh_nb[o] = nbr[(size_t)bn * cK + o];
        float d = dist[(size_t)bn * cK + o];
        float z = d * TAB_INV;
        int idx = (int)z;
        if (idx > TABN - 2) idx = TABN - 2;
        sh_idx[o] = idx;
        sh_frac[o] = fminf(z - (float)idx, 1.0f);
    }
    __syncthreads();   // barrier #1: sh_h / sh_nb / sh_idx / sh_frac visible

    // qt[h,c] = sum_k q[h,k]*wkl[k,c]  (wkl bias cancels in softmax) — wave-local
    const float* wklp = wkl_w + l * 1024;
    float qt = 0.f;
    #pragma unroll 8
    for (int k = 0; k < 32; k++) qt += __shfl(qv, srcb + k) * wklp[k * 32 + c];

    const __half2* kvb = kvr + (size_t)b * cN * cH;
    const float4* tab4 = (const float4*)tabP + (size_t)l * TABN * 32;

    // single fused pass: logits -> online softmax -> PV accumulate.
    // Per pair of edges: 2 half2 KV gathers + 1 float4 tab load (half-split across hi).
    float mrun = -1e30f, srun = 0.f, trun = 0.f;
    #pragma unroll 6
    for (int m = 0; m < cK; m += 2) {
        int j0 = sh_nb[m], j1 = sh_nb[m + 1];
        __half2 kv0 = kvb[(size_t)j0 * cH + o];
        __half2 kv1 = kvb[(size_t)j1 * cH + o];
        int mm = m + hi;
        int idx = sh_idx[mm];
        float fr = sh_frac[mm];
        float4 tp = tab4[(size_t)idx * 32 + c];
        float wkm = tp.x + fr * (tp.y - tp.x);
        float wvm = tp.z + fr * (tp.w - tp.z);
        float wko = __shfl_xor(wkm, 32);
        float wvo = __shfl_xor(wvm, 32);
        float wk0 = hi ? wko : wkm, wk1 = hi ? wkm : wko;
        float wv0 = hi ? wvo : wvm, wv1 = hi ? wvm : wvo;
        float k0 = __low2float(kv0), v0 = __high2float(kv0);
        float k1 = __low2float(kv1), v1 = __high2float(kv1);
        // butterfly logits (edge m on even c, edge m+1 on odd c)
        float pa = qt * wk0 * k0;
        float pb = qt * wk1 * k1;
        float x = (c & 1) ? pb : pa;
        float y = (c & 1) ? pa : pb;
        x += __shfl_xor(y, 1);
        x += __shfl_xor(x, 2);
        x += __shfl_xor(x, 4);
        x += __shfl_xor(x, 8);
        x += __shfl_xor(x, 16);
        float xo = __shfl_xor(x, 1);
        float xm  = (c & 1) ? xo : x;
        float xm1 = (c & 1) ? x : xo;
        // online softmax update (per-head state, replicated across the 32 lanes)
        float mnew = fmaxf(mrun, fmaxf(xm, xm1));
        float sc  = __expf(mrun - mnew);
        float em  = __expf(xm - mnew);
        float em1 = __expf(xm1 - mnew);
        srun = srun * sc + em + em1;
        trun = trun * sc + em * (wv0 * v0) + em1 * (wv1 * v1);
        mrun = mnew;
    }
    float tt = trun / srun;

    // aggr[c] = wvl_b + sum_i wvl[i][c] * t[h*32+i] — t stays in registers (wave-local shfl)
    const float* wvlTp = wvlT + l * 1024;
    float aggr = wvl_b[l * 32 + c];
    #pragma unroll 8
    for (int i = 0; i < 32; i++) aggr += wvlTp[i * 32 + c] * __shfl(tt, srcb + i);

    // x = cen_b + aggr + cen_w[o,:] . h  (sh_h read-only since barrier #1)
    const float* cenTp = cenT + (size_t)l * cH * cH;
    float x0 = 0.f, x1 = 0.f;
    #pragma unroll 4
    for (int i = 0; i < cH; i += 2) {
        x0 += cenTp[i * cH + o] * sh_h[i];
        x1 += cenTp[(i + 1) * cH + o] * sh_h[i + 1];
    }
    float x = cen_b[l * cH + o] + aggr + x0 + x1;

    // LayerNorm: per-wave 64-lane reduce, then 2-value cross-wave exchange
    float s1 = x, s2 = x * x;
    #pragma unroll
    for (int off = 32; off; off >>= 1) {
        s1 += __shfl_xor(s1, off);
        s2 += __shfl_xor(s2, off);
    }
    int wid = o >> 6;
    if (lane == 0) { red[wid][0] = s1; red[wid][1] = s2; }
    __syncthreads();   // barrier #2
    float tot1 = red[0][0] + red[1][0], tot2 = red[0][1] + red[1][1];
    float mu = tot1 * (1.0f / 128.0f);
    float var = tot2 * (1.0f / 128.0f) - mu * mu;
    float xn = (x - mu) * rsqrtf(var + 1e-5f);
    xn = xn * ln_g[l * cH + o] + ln_b[l * cH + o];
    float sx = sspf(xn);
    sh_t[o] = sx;
    __syncthreads();   // barrier #3

    // hnew = h + out_b + out_w[o,:] . ssp(xn)
    const float* outTp = outT + (size_t)l * cH * cH;
    float o0 = 0.f, o1 = 0.f;
    #pragma unroll 4
    for (int i = 0; i < cH; i += 2) {
        o0 += outTp[i * cH + o] * sh_t[i];
        o1 += outTp[(i + 1) * cH + o] * sh_t[i + 1];
    }
    float hnew = sh_h[o] + out_b[l * cH + o] + o0 + o1;
    h_out[(size_t)bn * cH + o] = hnew;

    // ---- fused qkv for layer l+1 — wave-local; K/V written interleaved ----
    if (l < cL - 1) {
        size_t wo = ((size_t)(l + 1) * 4 + hh) * 1024;
        const float* bq = wqT + wo;
        const float* bk = wkT + wo;
        const float* bv = wvT + wo;
        float sq = 0.f, sk = 0.f, sv = 0.f;
        #pragma unroll
        for (int d = 0; d < 32; d++) {
            float xv = __shfl(hnew, srcb + d);
            sq += bq[d * 32 + c] * xv;
            sk += bk[d * 32 + c] * xv;
            sv += bv[d * 32 + c] * xv;
        }
        qw[(size_t)bn * cH + o] = sq;
        kvw[(size_t)bn * cH + o] = __halves2half2(__float2half(sk), __float2half(sv));
    }
}

// ---------------- FC head ----------------
__global__ void __launch_bounds__(256) k_fc1p(const float* __restrict__ hbuf,
                                              const float* __restrict__ w,
                                              float* __restrict__ partial)
{
    int o = blockIdx.x >> 2, qp = blockIdx.x & 3;
    int tid = threadIdx.x;
    constexpr int CH = cFLAT / 4;
    const float4* wr = (const float4*)(w + (size_t)o * cFLAT + qp * CH);
    float a[4] = {0.f, 0.f, 0.f, 0.f};
    for (int i = tid; i < CH / 4; i += 256) {
        float4 wv = wr[i];
        #pragma unroll
        for (int bb = 0; bb < 4; bb++) {
            float4 hv = ((const float4*)(hbuf + (size_t)bb * cFLAT + qp * CH))[i];
            a[bb] += wv.x * hv.x + wv.y * hv.y + wv.z * hv.z + wv.w * hv.w;
        }
    }
    #pragma unroll
    for (int off = 32; off; off >>= 1) {
        #pragma unroll
        for (int bb = 0; bb < 4; bb++) a[bb] += __shfl_xor(a[bb], off);
    }
    __shared__ float red[4][4];
    if ((tid & 63) == 0) {
        #pragma unroll
        for (int bb = 0; bb < 4; bb++) red[tid >> 6][bb] = a[bb];
    }
    __syncthreads();
    if (tid < 4) {
        float s = red[0][tid] + red[1][tid] + red[2][tid] + red[3][tid];
        partial[((size_t)o * 4 + qp) * 4 + tid] = s;
    }
}

__global__ void __launch_bounds__(512) k_head2(const float* __restrict__ partial,
                                               const float* __restrict__ fc1_b,
                                               const float* __restrict__ fc2_w,
                                               const float* __restrict__ fc2_b,
                                               const float* __restrict__ fc3_w,
                                               const float* __restrict__ fc3_b,
                                               float* __restrict__ out)
{
    int tid = threadIdx.x;
    __shared__ float y1[4][128];
    __shared__ float y2[4][64];
    {
        int bb = tid >> 7, o = tid & 127;
        float s = fc1_b[o];
        #pragma unroll
        for (int qp = 0; qp < 4; qp++) s += partial[((size_t)o * 4 + qp) * 4 + bb];
        y1[bb][o] = fmaxf(s, 0.f);
    }
    __syncthreads();
    if (tid < 256) {
        int bb = tid >> 6, o = tid & 63;
        float s = fc2_b[o];
        #pragma unroll 8
        for (int i = 0; i < 128; i++) s += fc2_w[o * 128 + i] * y1[bb][i];
        y2[bb][o] = fmaxf(s, 0.f);
    }
    __syncthreads();
    if (tid < 4) {
        float s = fc3_b[0];
        #pragma unroll 8
        for (int i = 0; i < 64; i++) s += fc3_w[i] * y2[tid][i];
        out[tid] = s;
    }
}

extern "C" void kernel_launch(void* const* d_in, const int* in_sizes, int n_in,
                              void* d_out, int out_size, void* d_ws, size_t ws_size,
                              hipStream_t stream) {
    const float* state  = (const float*)d_in[0];
    const float* ppv    = (const float*)d_in[1];
    const float* w_prot = (const float*)d_in[2];
    const float* b_prot = (const float*)d_in[3];
    const float* w_lig  = (const float*)d_in[4];
    const float* b_lig  = (const float*)d_in[5];
    const float* wq     = (const float*)d_in[6];
    const float* wk     = (const float*)d_in[7];
    const float* wv     = (const float*)d_in[8];
    const float* wkn1_w = (const float*)d_in[9];
    const float* wkn1_b = (const float*)d_in[10];
    const float* wkn2_w = (const float*)d_in[11];
    const float* wkn2_b = (const float*)d_in[12];
    const float* wkl_w  = (const float*)d_in[13];
    const float* wvn1_w = (const float*)d_in[15];
    const float* wvn1_b = (const float*)d_in[16];
    const float* wvn2_w = (const float*)d_in[17];
    const float* wvn2_b = (const float*)d_in[18];
    const float* wvl_w  = (const float*)d_in[19];
    const float* wvl_b  = (const float*)d_in[20];
    const float* cen_w  = (const float*)d_in[21];
    const float* cen_b  = (const float*)d_in[22];
    const float* out_w  = (const float*)d_in[23];
    const float* out_b  = (const float*)d_in[24];
    const float* ln_g   = (const float*)d_in[25];
    const float* ln_b   = (const float*)d_in[26];
    const float* fc1_w  = (const float*)d_in[27];
    const float* fc1_b  = (const float*)d_in[28];
    const float* fc2_w  = (const float*)d_in[29];
    const float* fc2_b  = (const float*)d_in[30];
    const float* fc3_w  = (const float*)d_in[31];
    const float* fc3_b  = (const float*)d_in[32];

    float* ws = (float*)d_ws;
    size_t off = 0;
    float* pos   = ws + off; off += (size_t)cB * cN * 3;
    float* h_a   = ws + off; off += (size_t)cB * cN * cH;
    float* h_b   = ws + off; off += (size_t)cB * cN * cH;
    float* qA    = ws + off; off += (size_t)cB * cN * cH;
    float* qB    = ws + off; off += (size_t)cB * cN * cH;
    __half2* kvA = (__half2*)(ws + off); off += (size_t)cB * cN * cH;   // 1 half2 per (node,ch)
    __half2* kvB = (__half2*)(ws + off); off += (size_t)cB * cN * cH;
    float* distb = ws + off; off += (size_t)cEdges;
    int*   nbrb  = (int*)(ws + off); off += (size_t)cEdges;
    float* tabb  = ws + off; off += (size_t)cL * TABN * 128;  // float4 kv-pair table
    float* wqT   = ws + off; off += 24576;
    float* wkT   = ws + off; off += 24576;
    float* wvT   = ws + off; off += 24576;
    float* w1Tk  = ws + off; off += 24576;
    float* w1Tv  = ws + off; off += 24576;
    float* w2Tk  = ws + off; off += 6144;
    float* w2Tv  = ws + off; off += 6144;
    float* wvlT  = ws + off; off += 6144;
    float* cenT  = ws + off; off += 98304;
    float* outT  = ws + off; off += 98304;
    float* partial = ws + off; off += 2048;

    k_init<<<2720, 256, 0, stream>>>(wq, wk, wv, wkn1_w, wvn1_w, wkn2_w, wvn2_w,
                                     wvl_w, cen_w, out_w,
                                     wqT, wkT, wvT, w1Tk, w1Tv, w2Tk, w2Tv, wvlT, cenT, outT,
                                     state, ppv, w_prot, b_prot, w_lig, b_lig, h_a, pos);
    k_knn<<<cN + TABN / 4 + cB * cN / 2, 256, 0, stream>>>(
        pos, nbrb, distb,
        w1Tk, wkn1_b, w2Tk, wkn2_b, w1Tv, wvn1_b, w2Tv, wvn2_b, tabb,
        h_a, wqT, wkT, wvT, qA, kvA);

    float* hc = h_a;
    float* hn = h_b;
    for (int l = 0; l < cL; l++) {
        float* qr = (l & 1) ? qB : qA;
        __half2* kvr = (l & 1) ? kvB : kvA;
        float* qw2 = (l & 1) ? qA : qB;
        __half2* kvw2 = (l & 1) ? kvA : kvB;
        k_attn<<<cB * cN, 128, 0, stream>>>(l, hc, qr, kvr, nbrb, distb, tabb,
            wkl_w, wvlT, wvl_b, cenT, cen_b, outT, out_b, ln_g, ln_b,
            hn, qw2, kvw2, wqT, wkT, wvT);
        float* tmp = hc; hc = hn; hn = tmp;
    }

    k_fc1p<<<512, 256, 0, stream>>>(hc, fc1_w, partial);
    k_head2<<<1, 512, 0, stream>>>(partial, fc1_b, fc2_w, fc2_b, fc3_w, fc3_b, (float*)d_out);
}

// Round 14
// 274.809 us; speedup vs baseline: 1.0959x; 1.0959x over previous
//
#include <hip/hip_runtime.h>
#include <hip/hip_fp16.h>
#include <math.h>

constexpr int cB   = 4;
constexpr int cNL  = 150;
constexpr int cNP  = 550;
constexpr int cN   = 700;
constexpr int cH   = 128;
constexpr int cHeads = 4;
constexpr int cL   = 6;
constexpr int cK   = 48;
constexpr int cPF  = 27;
constexpr int cNC  = 13;
constexpr int cFLAT = cN * cH;       // 89600
constexpr int cEdges = cB * cN * cK; // 134400

constexpr int   TABN = 4096;
#define TAB_DMAX 11.0f
#define TAB_HT   (TAB_DMAX / (float)(TABN - 1))
#define TAB_INV  ((float)(TABN - 1) / TAB_DMAX)

#define RBF_STEP (10.0f / 127.0f)
#define RBF_COEFF (-0.5f / (RBF_STEP * RBF_STEP))
#define LOG2F_C 0.69314718055994530942f

__device__ __forceinline__ float sspf(float x) {
    float ax = fabsf(x);
    return fmaxf(x, 0.0f) + __logf(1.0f + __expf(-ax)) - LOG2F_C;
}

__device__ __forceinline__ int mbcnt64(unsigned long long m) {
    return __builtin_amdgcn_mbcnt_hi((unsigned)(m >> 32),
           __builtin_amdgcn_mbcnt_lo((unsigned)m, 0));
}

// ---------------- fused: weight transposes + embedding ----------------
__global__ void __launch_bounds__(256) k_init(
    const float* __restrict__ wq, const float* __restrict__ wk, const float* __restrict__ wv,
    const float* __restrict__ wkn1_w, const float* __restrict__ wvn1_w,
    const float* __restrict__ wkn2_w, const float* __restrict__ wvn2_w,
    const float* __restrict__ wvl_w,
    const float* __restrict__ cen_w, const float* __restrict__ out_w,
    float* __restrict__ wqT, float* __restrict__ wkT, float* __restrict__ wvT,
    float* __restrict__ w1Tk, float* __restrict__ w1Tv,
    float* __restrict__ w2Tk, float* __restrict__ w2Tv,
    float* __restrict__ wvlT,
    float* __restrict__ cenT, float* __restrict__ outT,
    const float* __restrict__ state, const float* __restrict__ ppv,
    const float* __restrict__ w_prot, const float* __restrict__ b_prot,
    const float* __restrict__ w_lig, const float* __restrict__ b_lig,
    float* __restrict__ h, float* __restrict__ pos)
{
    if (blockIdx.x < 1320) {
        int idx = blockIdx.x * 256 + threadIdx.x;
        if (idx < 3 * 24576) {
            int seg = idx / 24576, i = idx % 24576;
            const float* src = seg == 0 ? wq : (seg == 1 ? wk : wv);
            float* dst = seg == 0 ? wqT : (seg == 1 ? wkT : wvT);
            int l = i / 4096, r = i % 4096;
            int hh = r / 1024, r2 = r % 1024;
            int d = r2 / 32, k = r2 % 32;
            dst[i] = src[(((size_t)l * 4 + hh) * 32 + k) * 32 + d];
            return;
        }
        idx -= 3 * 24576;
        if (idx < 2 * 24576) {
            int seg = idx / 24576, i = idx % 24576;
            const float* src = seg == 0 ? wkn1_w : wvn1_w;
            float* dst = seg == 0 ? w1Tk : w1Tv;
            int l = i / 4096, r = i % 4096;
            int c = r / 32, o = r % 32;
            dst[i] = src[((size_t)l * 32 + o) * 128 + c];
            return;
        }
        idx -= 2 * 24576;
        if (idx < 3 * 6144) {
            int seg = idx / 6144, i = idx % 6144;
            const float* src = seg == 0 ? wkn2_w : (seg == 1 ? wvn2_w : wvl_w);
            float* dst = seg == 0 ? w2Tk : (seg == 1 ? w2Tv : wvlT);
            int l = i / 1024, r = i % 1024;
            int c = r / 32, o = r % 32;
            dst[i] = src[((size_t)l * 32 + o) * 32 + c];
            return;
        }
        idx -= 3 * 6144;
        int seg = idx / 98304, i = idx % 98304;
        const float* src = seg == 0 ? cen_w : out_w;
        float* dst = seg == 0 ? cenT : outT;
        int l = i / 16384, r = i % 16384;
        int ii = r / 128, o = r % 128;
        dst[i] = src[((size_t)l * 128 + o) * 128 + ii];
        return;
    }
    // ---- embed: 2 nodes per block ----
    int rel = blockIdx.x - 1320;
    int node = rel * 2 + (threadIdx.x >> 7);
    int b = node / cN, n = node % cN;
    int o = threadIdx.x & 127;
    int lane = threadIdx.x & 63;
    float out;
    if (n < cNP) {
        const float* src = ppv + ((size_t)b * cNP + n) * 30;
        float v = (lane < 30) ? src[lane] : 0.f;
        float s = b_prot[o];
        #pragma unroll
        for (int f = 0; f < cPF; f++) s += w_prot[o * cPF + f] * __shfl(v, 3 + f);
        out = s;
        if (o < 3) pos[((size_t)b * cN + n) * 3 + o] = v;
    } else {
        int nl = n - cNP;
        const float* src = state + ((size_t)b * cNL + nl) * 4;
        float v = (lane < 4) ? src[lane] : 0.f;
        int t = (int)__shfl(v, 3);
        out = w_lig[o * cNC + t] + b_lig[o];
        if (o < 3) pos[((size_t)b * cN + n) * 3 + o] = v;
    }
    h[((size_t)b * cN + n) * cH + o] = out;
}

// ---------------- KNN (radix-select) + edge-MLP table build (lerp-pair float2) + qkv(l=0) ----------------
__global__ void __launch_bounds__(256) k_knn(
    const float* __restrict__ pos, int* __restrict__ nbr, float* __restrict__ dist,
    const float* __restrict__ w1Tk, const float* __restrict__ wkn1_b,
    const float* __restrict__ w2Tk, const float* __restrict__ wkn2_b,
    const float* __restrict__ w1Tv, const float* __restrict__ wvn1_b,
    const float* __restrict__ w2Tv, const float* __restrict__ wvn2_b,
    float* __restrict__ tabP,
    const float* __restrict__ hbuf,
    const float* __restrict__ wqT, const float* __restrict__ wkT, const float* __restrict__ wvT,
    float* __restrict__ q0, __half2* __restrict__ kv0)
{
    int tid = threadIdx.x;
    if (blockIdx.x < cN) {
        // ---- knn: one wave per node, radix-select on float bit patterns ----
        int lane = tid & 63;
        int node = blockIdx.x * 4 + (tid >> 6);
        int b = node / cN, n = node % cN;
        const float* pb = pos + (size_t)b * cN * 3;
        float px = pb[n * 3 + 0], py = pb[n * 3 + 1], pz = pb[n * 3 + 2];
        float d2v[11];
        #pragma unroll
        for (int s = 0; s < 11; s++) {
            int j = lane + s * 64;
            float d2 = 1e30f;
            if (j < cN) {
                float dx = pb[j * 3 + 0] - px;
                float dy = pb[j * 3 + 1] - py;
                float dz = pb[j * 3 + 2] - pz;
                d2 = dx * dx + dy * dy + dz * dz;
                if (j == n) d2 = 1e9f;
            }
            d2v[s] = d2;
        }
        unsigned p = 0;
        for (int bit = 30; bit >= 0; --bit) {
            unsigned t = p | (1u << bit);
            int cnt = 0;
            #pragma unroll
            for (int s = 0; s < 11; s++)
                cnt += __popcll(__ballot(__float_as_uint(d2v[s]) < t));
            if (cnt <= 47) p = t;
        }
        int c_lt = 0;
        #pragma unroll
        for (int s = 0; s < 11; s++)
            c_lt += __popcll(__ballot(__float_as_uint(d2v[s]) < p));
        int base = 0, ebase = c_lt, need = 48 - c_lt;
        #pragma unroll
        for (int s = 0; s < 11; s++) {
            unsigned u = __float_as_uint(d2v[s]);
            unsigned long long blt = __ballot(u < p);
            unsigned long long beq = __ballot(u == p);
            int posn = -1;
            int bl = mbcnt64(blt);
            if (u < p) posn = base + bl;
            base += __popcll(blt);
            int r = mbcnt64(beq);
            int cs = __popcll(beq);
            int take = need < cs ? need : cs;
            if (u == p && r < take) posn = ebase + r;
            ebase += take; need -= take;
            if (posn >= 0) {
                nbr[(size_t)node * cK + posn] = s * 64 + lane;
                dist[(size_t)node * cK + posn] = sqrtf(d2v[s]);
            }
        }
        return;
    }
    if (blockIdx.x < cN + TABN / 4) {
        // ---- table build: wave per entry; lerp-pair layout:
        // float2 slot [(l*TABN+e)*2+side][c] = { val[e], val[e+1] }
        int rel = blockIdx.x - cN;
        int lane = tid & 63;
        int e = rel * 4 + (tid >> 6);
        int side = lane >> 5, o = lane & 31;
        float d = (float)e * TAB_HT;
        float z = d * (127.0f / 10.0f);
        int c0 = (int)floorf(z) - 7;
        c0 = c0 < 0 ? 0 : (c0 > 112 ? 112 : c0);
        int i = lane & 15;
        float tt = d - RBF_STEP * (float)(c0 + i);
        float eav = __expf(RBF_COEFF * tt * tt);
        const float* w1T = (side ? w1Tv : w1Tk);
        const float* b1  = (side ? wvn1_b : wkn1_b);
        const float* w2T = (side ? w2Tv : w2Tk);
        const float* b2  = (side ? wvn2_b : wkn2_b);
        int srcb = side * 32;
        for (int l = 0; l < cL; l++) {
            float s = b1[l * 32 + o];
            const float* w1p = w1T + (size_t)l * 4096;
            #pragma unroll
            for (int ii = 0; ii < 16; ii++)
                s += w1p[(c0 + ii) * 32 + o] * __shfl(eav, ii);
            float t1 = sspf(s);
            float s2 = b2[l * 32 + o];
            const float* w2p = w2T + (size_t)l * 1024;
            #pragma unroll
            for (int cc = 0; cc < 32; cc++)
                s2 += w2p[cc * 32 + o] * __shfl(t1, srcb + cc);
            tabP[((((size_t)l * TABN + e) * 2 + side) * 32 + o) * 2] = s2;
            if (e > 0)
                tabP[((((size_t)l * TABN + (e - 1)) * 2 + side) * 32 + o) * 2 + 1] = s2;
        }
        return;
    }
    // ---- qkv for layer 0: 2 nodes per block; K/V stored interleaved (half2) ----
    int bn = (blockIdx.x - cN - TABN / 4) * 2 + (tid >> 7);
    int o = tid & 127;
    int hh = o >> 5, kq = o & 31;
    float hval = hbuf[(size_t)bn * cH + o];
    size_t wo = ((size_t)0 * 4 + hh) * 1024;
    const float* bq = wqT + wo;
    const float* bk = wkT + wo;
    const float* bv = wvT + wo;
    int srcb = (hh & 1) * 32;
    float sq = 0.f, sk = 0.f, sv = 0.f;
    #pragma unroll
    for (int d = 0; d < 32; d++) {
        float x = __shfl(hval, srcb + d);
        sq += bq[d * 32 + kq] * x;
        sk += bk[d * 32 + kq] * x;
        sv += bv[d * 32 + kq] * x;
    }
    q0[(size_t)bn * cH + o] = sq;
    kv0[(size_t)bn * cH + o] = __halves2half2(__float2half(sk), __float2half(sv));
}

// ---------------- fused attention + LN + residual MLP + next-layer qkv ----------------
// FINAL (best verified, 275.5 us total): R6 structure (128T/node, 3 barriers)
// with ONLINE SOFTMAX: single gather loop fuses QK^T, softmax, and PV. V arrives
// in the same half2 as K and is consumed IMMEDIATELY (no stash). One memory-drain
// phase per layer instead of two.
__global__ void __launch_bounds__(128) k_attn(
    int l,
    const float* __restrict__ h_in, const float* __restrict__ qr,
    const __half2* __restrict__ kvr,
    const int* __restrict__ nbr, const float* __restrict__ dist,
    const float* __restrict__ tabP,
    const float* __restrict__ wkl_w,
    const float* __restrict__ wvlT, const float* __restrict__ wvl_b,
    const float* __restrict__ cenT, const float* __restrict__ cen_b,
    const float* __restrict__ outT, const float* __restrict__ out_b,
    const float* __restrict__ ln_g, const float* __restrict__ ln_b,
    float* __restrict__ h_out,
    float* __restrict__ qw, __half2* __restrict__ kvw,
    const float* __restrict__ wqT, const float* __restrict__ wkT, const float* __restrict__ wvT)
{
    int o = threadIdx.x;              // 0..127
    int lane = o & 63;
    int bn = blockIdx.x;
    int b = bn / cN;
    int hh = o >> 5, c = o & 31;
    int srcb = (hh & 1) * 32;
    int hi = lane >> 5;               // 0: lower half-wave, 1: upper

    __shared__ float sh_h[cH];
    __shared__ float sh_t[cH];
    __shared__ int   sh_nb[cK];
    __shared__ int   sh_idx[cK];
    __shared__ float sh_frac[cK];
    __shared__ float red[2][2];

    sh_h[o] = h_in[(size_t)bn * cH + o];
    float qv = qr[(size_t)bn * cH + o];
    if (o < cK) {
        sh_nb[o] = nbr[(size_t)bn * cK + o];
        float d = dist[(size_t)bn * cK + o];
        float z = d * TAB_INV;
        int idx = (int)z;
        if (idx > TABN - 2) idx = TABN - 2;
        sh_idx[o] = idx;
        sh_frac[o] = fminf(z - (float)idx, 1.0f);
    }
    __syncthreads();   // barrier #1: sh_h / sh_nb / sh_idx / sh_frac visible

    // qt[h,c] = sum_k q[h,k]*wkl[k,c]  (wkl bias cancels in softmax) — wave-local
    const float* wklp = wkl_w + l * 1024;
    float qt = 0.f;
    #pragma unroll 8
    for (int k = 0; k < 32; k++) qt += __shfl(qv, srcb + k) * wklp[k * 32 + c];

    const __half2* kvb = kvr + (size_t)b * cN * cH;
    const float2* tab2 = (const float2*)tabP + (size_t)l * TABN * 64;

    // single fused pass: logits -> online softmax -> PV accumulate.
    // Per pair of edges: 2 half2 KV gathers + 2 float2 tab lerps (half-split across hi).
    float mrun = -1e30f, srun = 0.f, trun = 0.f;
    #pragma unroll 4
    for (int m = 0; m < cK; m += 2) {
        int j0 = sh_nb[m], j1 = sh_nb[m + 1];
        __half2 kv0 = kvb[(size_t)j0 * cH + o];
        __half2 kv1 = kvb[(size_t)j1 * cH + o];
        int mm = m + hi;
        int idx = sh_idx[mm];
        float fr = sh_frac[mm];
        float2 tk = tab2[((size_t)idx * 2 + 0) * 32 + c];
        float2 tv = tab2[((size_t)idx * 2 + 1) * 32 + c];
        float wkm = tk.x + fr * (tk.y - tk.x);
        float wvm = tv.x + fr * (tv.y - tv.x);
        float wko = __shfl_xor(wkm, 32);
        float wvo = __shfl_xor(wvm, 32);
        float wk0 = hi ? wko : wkm, wk1 = hi ? wkm : wko;
        float wv0 = hi ? wvo : wvm, wv1 = hi ? wvm : wvo;
        float k0 = __low2float(kv0), v0 = __high2float(kv0);
        float k1 = __low2float(kv1), v1 = __high2float(kv1);
        // butterfly logits (edge m on even c, edge m+1 on odd c)
        float pa = qt * wk0 * k0;
        float pb = qt * wk1 * k1;
        float x = (c & 1) ? pb : pa;
        float y = (c & 1) ? pa : pb;
        x += __shfl_xor(y, 1);
        x += __shfl_xor(x, 2);
        x += __shfl_xor(x, 4);
        x += __shfl_xor(x, 8);
        x += __shfl_xor(x, 16);
        float xo = __shfl_xor(x, 1);
        float xm  = (c & 1) ? xo : x;
        float xm1 = (c & 1) ? x : xo;
        // online softmax update (per-head state, replicated across the 32 lanes)
        float mnew = fmaxf(mrun, fmaxf(xm, xm1));
        float sc  = __expf(mrun - mnew);
        float em  = __expf(xm - mnew);
        float em1 = __expf(xm1 - mnew);
        srun = srun * sc + em + em1;
        trun = trun * sc + em * (wv0 * v0) + em1 * (wv1 * v1);
        mrun = mnew;
    }
    float tt = trun / srun;

    // aggr[c] = wvl_b + sum_i wvl[i][c] * t[h*32+i] — t stays in registers (wave-local shfl)
    const float* wvlTp = wvlT + l * 1024;
    float aggr = wvl_b[l * 32 + c];
    #pragma unroll 8
    for (int i = 0; i < 32; i++) aggr += wvlTp[i * 32 + c] * __shfl(tt, srcb + i);

    // x = cen_b + aggr + cen_w[o,:] . h  (sh_h read-only since barrier #1)
    const float* cenTp = cenT + (size_t)l * cH * cH;
    float x0 = 0.f, x1 = 0.f;
    #pragma unroll 4
    for (int i = 0; i < cH; i += 2) {
        x0 += cenTp[i * cH + o] * sh_h[i];
        x1 += cenTp[(i + 1) * cH + o] * sh_h[i + 1];
    }
    float x = cen_b[l * cH + o] + aggr + x0 + x1;

    // LayerNorm: per-wave 64-lane reduce, then 2-value cross-wave exchange
    float s1 = x, s2 = x * x;
    #pragma unroll
    for (int off = 32; off; off >>= 1) {
        s1 += __shfl_xor(s1, off);
        s2 += __shfl_xor(s2, off);
    }
    int wid = o >> 6;
    if (lane == 0) { red[wid][0] = s1; red[wid][1] = s2; }
    __syncthreads();   // barrier #2
    float tot1 = red[0][0] + red[1][0], tot2 = red[0][1] + red[1][1];
    float mu = tot1 * (1.0f / 128.0f);
    float var = tot2 * (1.0f / 128.0f) - mu * mu;
    float xn = (x - mu) * rsqrtf(var + 1e-5f);
    xn = xn * ln_g[l * cH + o] + ln_b[l * cH + o];
    float sx = sspf(xn);
    sh_t[o] = sx;
    __syncthreads();   // barrier #3

    // hnew = h + out_b + out_w[o,:] . ssp(xn)
    const float* outTp = outT + (size_t)l * cH * cH;
    float o0 = 0.f, o1 = 0.f;
    #pragma unroll 4
    for (int i = 0; i < cH; i += 2) {
        o0 += outTp[i * cH + o] * sh_t[i];
        o1 += outTp[(i + 1) * cH + o] * sh_t[i + 1];
    }
    float hnew = sh_h[o] + out_b[l * cH + o] + o0 + o1;
    h_out[(size_t)bn * cH + o] = hnew;

    // ---- fused qkv for layer l+1 — wave-local; K/V written interleaved ----
    if (l < cL - 1) {
        size_t wo = ((size_t)(l + 1) * 4 + hh) * 1024;
        const float* bq = wqT + wo;
        const float* bk = wkT + wo;
        const float* bv = wvT + wo;
        float sq = 0.f, sk = 0.f, sv = 0.f;
        #pragma unroll
        for (int d = 0; d < 32; d++) {
            float xv = __shfl(hnew, srcb + d);
            sq += bq[d * 32 + c] * xv;
            sk += bk[d * 32 + c] * xv;
            sv += bv[d * 32 + c] * xv;
        }
        qw[(size_t)bn * cH + o] = sq;
        kvw[(size_t)bn * cH + o] = __halves2half2(__float2half(sk), __float2half(sv));
    }
}

// ---------------- FC head ----------------
__global__ void __launch_bounds__(256) k_fc1p(const float* __restrict__ hbuf,
                                              const float* __restrict__ w,
                                              float* __restrict__ partial)
{
    int o = blockIdx.x >> 2, qp = blockIdx.x & 3;
    int tid = threadIdx.x;
    constexpr int CH = cFLAT / 4;
    const float4* wr = (const float4*)(w + (size_t)o * cFLAT + qp * CH);
    float a[4] = {0.f, 0.f, 0.f, 0.f};
    for (int i = tid; i < CH / 4; i += 256) {
        float4 wv = wr[i];
        #pragma unroll
        for (int bb = 0; bb < 4; bb++) {
            float4 hv = ((const float4*)(hbuf + (size_t)bb * cFLAT + qp * CH))[i];
            a[bb] += wv.x * hv.x + wv.y * hv.y + wv.z * hv.z + wv.w * hv.w;
        }
    }
    #pragma unroll
    for (int off = 32; off; off >>= 1) {
        #pragma unroll
        for (int bb = 0; bb < 4; bb++) a[bb] += __shfl_xor(a[bb], off);
    }
    __shared__ float red[4][4];
    if ((tid & 63) == 0) {
        #pragma unroll
        for (int bb = 0; bb < 4; bb++) red[tid >> 6][bb] = a[bb];
    }
    __syncthreads();
    if (tid < 4) {
        float s = red[0][tid] + red[1][tid] + red[2][tid] + red[3][tid];
        partial[((size_t)o * 4 + qp) * 4 + tid] = s;
    }
}

__global__ void __launch_bounds__(512) k_head2(const float* __restrict__ partial,
                                               const float* __restrict__ fc1_b,
                                               const float* __restrict__ fc2_w,
                                               const float* __restrict__ fc2_b,
                                               const float* __restrict__ fc3_w,
                                               const float* __restrict__ fc3_b,
                                               float* __restrict__ out)
{
    int tid = threadIdx.x;
    __shared__ float y1[4][128];
    __shared__ float y2[4][64];
    {
        int bb = tid >> 7, o = tid & 127;
        float s = fc1_b[o];
        #pragma unroll
        for (int qp = 0; qp < 4; qp++) s += partial[((size_t)o * 4 + qp) * 4 + bb];
        y1[bb][o] = fmaxf(s, 0.f);
    }
    __syncthreads();
    if (tid < 256) {
        int bb = tid >> 6, o = tid & 63;
        float s = fc2_b[o];
        #pragma unroll 8
        for (int i = 0; i < 128; i++) s += fc2_w[o * 128 + i] * y1[bb][i];
        y2[bb][o] = fmaxf(s, 0.f);
    }
    __syncthreads();
    if (tid < 4) {
        float s = fc3_b[0];
        #pragma unroll 8
        for (int i = 0; i < 64; i++) s += fc3_w[i] * y2[tid][i];
        out[tid] = s;
    }
}

extern "C" void kernel_launch(void* const* d_in, const int* in_sizes, int n_in,
                              void* d_out, int out_size, void* d_ws, size_t ws_size,
                              hipStream_t stream) {
    const float* state  = (const float*)d_in[0];
    const float* ppv    = (const float*)d_in[1];
    const float* w_prot = (const float*)d_in[2];
    const float* b_prot = (const float*)d_in[3];
    const float* w_lig  = (const float*)d_in[4];
    const float* b_lig  = (const float*)d_in[5];
    const float* wq     = (const float*)d_in[6];
    const float* wk     = (const float*)d_in[7];
    const float* wv     = (const float*)d_in[8];
    const float* wkn1_w = (const float*)d_in[9];
    const float* wkn1_b = (const float*)d_in[10];
    const float* wkn2_w = (const float*)d_in[11];
    const float* wkn2_b = (const float*)d_in[12];
    const float* wkl_w  = (const float*)d_in[13];
    const float* wvn1_w = (const float*)d_in[15];
    const float* wvn1_b = (const float*)d_in[16];
    const float* wvn2_w = (const float*)d_in[17];
    const float* wvn2_b = (const float*)d_in[18];
    const float* wvl_w  = (const float*)d_in[19];
    const float* wvl_b  = (const float*)d_in[20];
    const float* cen_w  = (const float*)d_in[21];
    const float* cen_b  = (const float*)d_in[22];
    const float* out_w  = (const float*)d_in[23];
    const float* out_b  = (const float*)d_in[24];
    const float* ln_g   = (const float*)d_in[25];
    const float* ln_b   = (const float*)d_in[26];
    const float* fc1_w  = (const float*)d_in[27];
    const float* fc1_b  = (const float*)d_in[28];
    const float* fc2_w  = (const float*)d_in[29];
    const float* fc2_b  = (const float*)d_in[30];
    const float* fc3_w  = (const float*)d_in[31];
    const float* fc3_b  = (const float*)d_in[32];

    float* ws = (float*)d_ws;
    size_t off = 0;
    float* pos   = ws + off; off += (size_t)cB * cN * 3;
    float* h_a   = ws + off; off += (size_t)cB * cN * cH;
    float* h_b   = ws + off; off += (size_t)cB * cN * cH;
    float* qA    = ws + off; off += (size_t)cB * cN * cH;
    float* qB    = ws + off; off += (size_t)cB * cN * cH;
    __half2* kvA = (__half2*)(ws + off); off += (size_t)cB * cN * cH;   // 1 half2 per (node,ch)
    __half2* kvB = (__half2*)(ws + off); off += (size_t)cB * cN * cH;
    float* distb = ws + off; off += (size_t)cEdges;
    int*   nbrb  = (int*)(ws + off); off += (size_t)cEdges;
    float* tabb  = ws + off; off += (size_t)cL * TABN * 64 * 2;  // lerp-pair float2
    float* wqT   = ws + off; off += 24576;
    float* wkT   = ws + off; off += 24576;
    float* wvT   = ws + off; off += 24576;
    float* w1Tk  = ws + off; off += 24576;
    float* w1Tv  = ws + off; off += 24576;
    float* w2Tk  = ws + off; off += 6144;
    float* w2Tv  = ws + off; off += 6144;
    float* wvlT  = ws + off; off += 6144;
    float* cenT  = ws + off; off += 98304;
    float* outT  = ws + off; off += 98304;
    float* partial = ws + off; off += 2048;

    k_init<<<2720, 256, 0, stream>>>(wq, wk, wv, wkn1_w, wvn1_w, wkn2_w, wvn2_w,
                                     wvl_w, cen_w, out_w,
                                     wqT, wkT, wvT, w1Tk, w1Tv, w2Tk, w2Tv, wvlT, cenT, outT,
                                     state, ppv, w_prot, b_prot, w_lig, b_lig, h_a, pos);
    k_knn<<<cN + TABN / 4 + cB * cN / 2, 256, 0, stream>>>(
        pos, nbrb, distb,
        w1Tk, wkn1_b, w2Tk, wkn2_b, w1Tv, wvn1_b, w2Tv, wvn2_b, tabb,
        h_a, wqT, wkT, wvT, qA, kvA);

    float* hc = h_a;
    float* hn = h_b;
    for (int l = 0; l < cL; l++) {
        float* qr = (l & 1) ? qB : qA;
        __half2* kvr = (l & 1) ? kvB : kvA;
        float* qw2 = (l & 1) ? qA : qB;
        __half2* kvw2 = (l & 1) ? kvA : kvB;
        k_attn<<<cB * cN, 128, 0, stream>>>(l, hc, qr, kvr, nbrb, distb, tabb,
            wkl_w, wvlT, wvl_b, cenT, cen_b, outT, out_b, ln_g, ln_b,
            hn, qw2, kvw2, wqT, wkT, wvT);
        float* tmp = hc; hc = hn; hn = tmp;
    }

    k_fc1p<<<512, 256, 0, stream>>>(hc, fc1_w, partial);
    k_head2<<<1, 512, 0, stream>>>(partial, fc1_b, fc2_w, fc2_b, fc3_w, fc3_b, (float*)d_out);
}